// Round 1
// baseline (20265.906 us; speedup 1.0000x reference)
//
#include <hip/hip_runtime.h>

constexpr int N_NODES = 100000;
constexpr int N_EDGES = 3200000;
constexpr float EPS = 1e-6f;
constexpr int LSTR = 129;   // LDS row stride (pad +1: b-reads conflict-free, a-reads 2-way=free)

// ---------------------------------------------------------------------------
// GEMM: Y[n, o] = sum_i X[n,i] * W(o,i)  (+bias) (+relu)
// W_OUT_IN=true  -> W stored [OUT_F, 128] (torch Linear weight)
// W_OUT_IN=false -> W stored [128, OUT_F] (gc weights, x @ W)
// Block: 256 thr, tile 64 nodes x OUT_F outs. Thread tile 4 x (OUT_F/16).
// ---------------------------------------------------------------------------
template<int OUT_F, bool W_OUT_IN, bool RELU, bool BIAS>
__global__ __launch_bounds__(256) void gemm_k(
    const float* __restrict__ X, const float* __restrict__ W,
    const float* __restrict__ bias, float* __restrict__ Y)
{
    __shared__ float xs[64 * LSTR];
    __shared__ float wsm[OUT_F * LSTR];
    const int tid = threadIdx.x;
    const int n_base = blockIdx.x * 64;

    // Stage W into LDS as [o][i], stride LSTR.
    if (W_OUT_IN) {
        for (int idx = tid; idx < OUT_F * 128; idx += 256) {
            int o = idx >> 7, i = idx & 127;
            wsm[o * LSTR + i] = W[idx];
        }
    } else {
        for (int idx = tid; idx < OUT_F * 128; idx += 256) {
            int i = idx / OUT_F, o = idx & (OUT_F - 1);
            wsm[o * LSTR + i] = W[idx];        // coalesced read, conflict-free write
        }
    }
    // Stage X tile (zero-pad past N).
    for (int idx = tid; idx < 64 * 128; idx += 256) {
        int r = idx >> 7, i = idx & 127;
        int n = n_base + r;
        xs[r * LSTR + i] = (n < N_NODES) ? X[(long)n * 128 + i] : 0.f;
    }
    __syncthreads();

    constexpr int TO = OUT_F / 16;
    const int ng = tid & 15;       // node group: 4 nodes
    const int og = tid >> 4;       // out group: TO outputs
    float acc[4][TO];
#pragma unroll
    for (int j = 0; j < 4; j++)
#pragma unroll
        for (int jo = 0; jo < TO; jo++) acc[j][jo] = 0.f;

    const float* xp = &xs[ng * 4 * LSTR];
    const float* wp = &wsm[og * TO * LSTR];
#pragma unroll 4
    for (int k = 0; k < 128; k++) {
        float a[4], b[TO];
#pragma unroll
        for (int j = 0; j < 4; j++) a[j] = xp[j * LSTR + k];
#pragma unroll
        for (int jo = 0; jo < TO; jo++) b[jo] = wp[jo * LSTR + k];
#pragma unroll
        for (int j = 0; j < 4; j++)
#pragma unroll
            for (int jo = 0; jo < TO; jo++)
                acc[j][jo] = fmaf(a[j], b[jo], acc[j][jo]);
    }

#pragma unroll
    for (int j = 0; j < 4; j++) {
        int n = n_base + ng * 4 + j;
        if (n < N_NODES) {
#pragma unroll
            for (int jo = 0; jo < TO; jo++) {
                float v = acc[j][jo];
                if (BIAS) v += bias[og * TO + jo];
                if (RELU) v = fmaxf(v, 0.f);
                Y[(long)n * OUT_F + og * TO + jo] = v;
            }
        }
    }
}

// ---------------------------------------------------------------------------
// LayerNorm, torch semantics: unbiased std (ddof=1), eps added to STD.
// One 64-lane wave per 128-wide row; 4 rows per 256-thread block.
// ---------------------------------------------------------------------------
__global__ __launch_bounds__(256) void ln_k(
    const float* __restrict__ in, const float* __restrict__ gamma,
    const float* __restrict__ beta, float* __restrict__ out)
{
    int row = blockIdx.x * 4 + (threadIdx.x >> 6);
    int lane = threadIdx.x & 63;
    if (row >= N_NODES) return;
    float x0 = in[(long)row * 128 + lane];
    float x1 = in[(long)row * 128 + 64 + lane];
    float s = x0 + x1;
    float sq = x0 * x0 + x1 * x1;
#pragma unroll
    for (int off = 32; off >= 1; off >>= 1) {
        s  += __shfl_xor(s, off, 64);
        sq += __shfl_xor(sq, off, 64);
    }
    float mean = s * (1.f / 128.f);
    float var  = fmaxf((sq - 128.f * mean * mean) * (1.f / 127.f), 0.f);
    float inv  = 1.f / (sqrtf(var) + EPS);
    out[(long)row * 128 + lane]      = gamma[lane]      * (x0 - mean) * inv + beta[lane];
    out[(long)row * 128 + 64 + lane] = gamma[lane + 64] * (x1 - mean) * inv + beta[lane + 64];
}

// ---------------------------------------------------------------------------
// Edge scatter: C[rows[e], :] += vals[e] * S[cols[e], :]
// OUT_F/4 lanes per edge, float4 gather, 4 scalar fp32 atomics per lane.
// ---------------------------------------------------------------------------
template<int OUT_F>
__global__ __launch_bounds__(256) void scatter_k(
    const int* __restrict__ rows, const int* __restrict__ cols,
    const float* __restrict__ vals, const float* __restrict__ S,
    float* __restrict__ C)
{
    constexpr int TPE = OUT_F / 4;
    int gid = blockIdx.x * 256 + threadIdx.x;
    int e = gid / TPE;
    int l = gid & (TPE - 1);
    if (e >= N_EDGES) return;
    int c = cols[e];
    int r = rows[e];
    float v = vals[e];
    float4 sv = ((const float4*)S)[(long)c * TPE + l];
    float* dst = C + (long)r * OUT_F + l * 4;
    atomicAdd(dst + 0, v * sv.x);
    atomicAdd(dst + 1, v * sv.y);
    atomicAdd(dst + 2, v * sv.z);
    atomicAdd(dst + 3, v * sv.w);
}

// ---------------------------------------------------------------------------
// ReLU copy (float4).
// ---------------------------------------------------------------------------
__global__ __launch_bounds__(256) void relu_k(
    const float* __restrict__ in, float* __restrict__ out, int n4)
{
    int i = blockIdx.x * 256 + threadIdx.x;
    if (i >= n4) return;
    float4 v = ((const float4*)in)[i];
    v.x = fmaxf(v.x, 0.f); v.y = fmaxf(v.y, 0.f);
    v.z = fmaxf(v.z, 0.f); v.w = fmaxf(v.w, 0.f);
    ((float4*)out)[i] = v;
}

extern "C" void kernel_launch(void* const* d_in, const int* in_sizes, int n_in,
                              void* d_out, int out_size, void* d_ws, size_t ws_size,
                              hipStream_t stream)
{
    const float* x     = (const float*)d_in[0];
    const int*   erows = (const int*)d_in[1];
    const int*   ecols = (const int*)d_in[2];
    const float* evals = (const float*)d_in[3];
    const float* fc1_w = (const float*)d_in[4];
    const float* fc1_b = (const float*)d_in[5];
    const float* fc2_w = (const float*)d_in[6];
    const float* fc2_b = (const float*)d_in[7];
    const float* ln_g  = (const float*)d_in[8];
    const float* ln_b  = (const float*)d_in[9];
    const float* gc_wn[4] = {(const float*)d_in[10], (const float*)d_in[13],
                             (const float*)d_in[16], (const float*)d_in[19]};
    const float* gc_wsq[4] = {(const float*)d_in[11], (const float*)d_in[14],
                              (const float*)d_in[17], (const float*)d_in[20]};
    const float* gc_b[4]  = {(const float*)d_in[12], (const float*)d_in[15],
                             (const float*)d_in[18], (const float*)d_in[21]};

    float* A = (float*)d_ws;                       // [N, 128]
    float* B = A + (size_t)N_NODES * 128;          // [N, 128]
    float* S = B + (size_t)N_NODES * 128;          // [N, 128]
    float* out = (float*)d_out;                    // [N, 64]

    dim3 blk(256);
    int gemm_grid = (N_NODES + 63) / 64;

    // fc1 -> A, fc2 -> B, LN -> A
    gemm_k<128, true, true, true><<<gemm_grid, blk, 0, stream>>>(x, fc1_w, fc1_b, A);
    gemm_k<128, true, true, true><<<gemm_grid, blk, 0, stream>>>(A, fc2_w, fc2_b, B);
    ln_k<<<(N_NODES + 3) / 4, blk, 0, stream>>>(B, ln_g, ln_b, A);

    // gc1..gc3 (128 -> 128): S = A@wn ; B = A@ws + b ; scatter ; relu -> A
    for (int l = 0; l < 3; l++) {
        gemm_k<128, false, false, false><<<gemm_grid, blk, 0, stream>>>(A, gc_wn[l], nullptr, S);
        gemm_k<128, false, false, true><<<gemm_grid, blk, 0, stream>>>(A, gc_wsq[l], gc_b[l], B);
        scatter_k<128><<<(N_EDGES * 32) / 256, blk, 0, stream>>>(erows, ecols, evals, S, B);
        relu_k<<<(N_NODES * 32 + 255) / 256, blk, 0, stream>>>(B, A, N_NODES * 32);
    }

    // gc4 (128 -> 64): final relu straight into d_out
    gemm_k<64, false, false, false><<<gemm_grid, blk, 0, stream>>>(A, gc_wn[3], nullptr, S);
    gemm_k<64, false, false, true><<<gemm_grid, blk, 0, stream>>>(A, gc_wsq[3], gc_b[3], B);
    scatter_k<64><<<(N_EDGES * 16) / 256, blk, 0, stream>>>(erows, ecols, evals, S, B);
    relu_k<<<(N_NODES * 16 + 255) / 256, blk, 0, stream>>>(B, out, N_NODES * 16);
}

// Round 2
// 2674.810 us; speedup vs baseline: 7.5766x; 7.5766x over previous
//
#include <hip/hip_runtime.h>

constexpr int N_NODES = 100000;
constexpr int N_EDGES = 3200000;
constexpr float EPS = 1e-6f;
constexpr int LSTR = 129;   // LDS row stride (pad +1)

constexpr int SCAN_CHUNK = 256;
constexpr int SCAN_NBLK = (N_NODES + SCAN_CHUNK - 1) / SCAN_CHUNK;   // 391

// ---------------------------------------------------------------------------
// GEMM: Y[n, o] = sum_i X[n,i] * W(o,i)  (+bias) (+relu)
// W_OUT_IN=true  -> W stored [OUT_F, 128] (torch Linear weight)
// W_OUT_IN=false -> W stored [128, OUT_F] (gc weights, x @ W)
// ---------------------------------------------------------------------------
template<int OUT_F, bool W_OUT_IN, bool RELU, bool BIAS>
__global__ __launch_bounds__(256) void gemm_k(
    const float* __restrict__ X, const float* __restrict__ W,
    const float* __restrict__ bias, float* __restrict__ Y)
{
    __shared__ float xs[64 * LSTR];
    __shared__ float wsm[OUT_F * LSTR];
    const int tid = threadIdx.x;
    const int n_base = blockIdx.x * 64;

    if (W_OUT_IN) {
        for (int idx = tid; idx < OUT_F * 128; idx += 256) {
            int o = idx >> 7, i = idx & 127;
            wsm[o * LSTR + i] = W[idx];
        }
    } else {
        for (int idx = tid; idx < OUT_F * 128; idx += 256) {
            int i = idx / OUT_F, o = idx & (OUT_F - 1);
            wsm[o * LSTR + i] = W[idx];
        }
    }
    for (int idx = tid; idx < 64 * 128; idx += 256) {
        int r = idx >> 7, i = idx & 127;
        int n = n_base + r;
        xs[r * LSTR + i] = (n < N_NODES) ? X[(long)n * 128 + i] : 0.f;
    }
    __syncthreads();

    constexpr int TO = OUT_F / 16;
    const int ng = tid & 15;
    const int og = tid >> 4;
    float acc[4][TO];
#pragma unroll
    for (int j = 0; j < 4; j++)
#pragma unroll
        for (int jo = 0; jo < TO; jo++) acc[j][jo] = 0.f;

    const float* xp = &xs[ng * 4 * LSTR];
    const float* wp = &wsm[og * TO * LSTR];
#pragma unroll 4
    for (int k = 0; k < 128; k++) {
        float a[4], b[TO];
#pragma unroll
        for (int j = 0; j < 4; j++) a[j] = xp[j * LSTR + k];
#pragma unroll
        for (int jo = 0; jo < TO; jo++) b[jo] = wp[jo * LSTR + k];
#pragma unroll
        for (int j = 0; j < 4; j++)
#pragma unroll
            for (int jo = 0; jo < TO; jo++)
                acc[j][jo] = fmaf(a[j], b[jo], acc[j][jo]);
    }

#pragma unroll
    for (int j = 0; j < 4; j++) {
        int n = n_base + ng * 4 + j;
        if (n < N_NODES) {
#pragma unroll
            for (int jo = 0; jo < TO; jo++) {
                float v = acc[j][jo];
                if (BIAS) v += bias[og * TO + jo];
                if (RELU) v = fmaxf(v, 0.f);
                Y[(long)n * OUT_F + og * TO + jo] = v;
            }
        }
    }
}

// ---------------------------------------------------------------------------
// LayerNorm (torch: unbiased std, eps added to std). 1 wave / 128-wide row.
// ---------------------------------------------------------------------------
__global__ __launch_bounds__(256) void ln_k(
    const float* __restrict__ in, const float* __restrict__ gamma,
    const float* __restrict__ beta, float* __restrict__ out)
{
    int row = blockIdx.x * 4 + (threadIdx.x >> 6);
    int lane = threadIdx.x & 63;
    if (row >= N_NODES) return;
    float x0 = in[(long)row * 128 + lane];
    float x1 = in[(long)row * 128 + 64 + lane];
    float s = x0 + x1;
    float sq = x0 * x0 + x1 * x1;
#pragma unroll
    for (int off = 32; off >= 1; off >>= 1) {
        s  += __shfl_xor(s, off, 64);
        sq += __shfl_xor(sq, off, 64);
    }
    float mean = s * (1.f / 128.f);
    float var  = fmaxf((sq - 128.f * mean * mean) * (1.f / 127.f), 0.f);
    float inv  = 1.f / (sqrtf(var) + EPS);
    out[(long)row * 128 + lane]      = gamma[lane]      * (x0 - mean) * inv + beta[lane];
    out[(long)row * 128 + 64 + lane] = gamma[lane + 64] * (x1 - mean) * inv + beta[lane + 64];
}

// ---------------------------------------------------------------------------
// CSR build: histogram -> 2-level exclusive scan -> fill (permute col/val).
// ---------------------------------------------------------------------------
__global__ __launch_bounds__(256) void hist_k(const int* __restrict__ rows, int* cnt)
{
    int e = blockIdx.x * 256 + threadIdx.x;
    if (e < N_EDGES) atomicAdd(&cnt[rows[e]], 1);
}

__global__ __launch_bounds__(256) void scan_phase1(const int* __restrict__ cnt, int* partials)
{
    __shared__ int sdata[SCAN_CHUNK];
    int i = blockIdx.x * SCAN_CHUNK + threadIdx.x;
    sdata[threadIdx.x] = (i < N_NODES) ? cnt[i] : 0;
    __syncthreads();
    for (int s = SCAN_CHUNK / 2; s > 0; s >>= 1) {
        if (threadIdx.x < s) sdata[threadIdx.x] += sdata[threadIdx.x + s];
        __syncthreads();
    }
    if (threadIdx.x == 0) partials[blockIdx.x] = sdata[0];
}

__global__ __launch_bounds__(512) void scan_phase2(int* partials)
{
    __shared__ int sdata[512];
    int t = threadIdx.x;
    int v = (t < SCAN_NBLK) ? partials[t] : 0;
    sdata[t] = v;
    __syncthreads();
    for (int off = 1; off < 512; off <<= 1) {
        int add = (t >= off) ? sdata[t - off] : 0;
        __syncthreads();
        sdata[t] += add;
        __syncthreads();
    }
    if (t < SCAN_NBLK) partials[t] = sdata[t] - v;   // exclusive
}

__global__ __launch_bounds__(256) void scan_phase3(
    const int* __restrict__ cnt, const int* __restrict__ partials, int* row_ptr)
{
    __shared__ int sdata[SCAN_CHUNK];
    int i = blockIdx.x * SCAN_CHUNK + threadIdx.x;
    int v = (i < N_NODES) ? cnt[i] : 0;
    sdata[threadIdx.x] = v;
    __syncthreads();
    for (int off = 1; off < SCAN_CHUNK; off <<= 1) {
        int add = (threadIdx.x >= off) ? sdata[threadIdx.x - off] : 0;
        __syncthreads();
        sdata[threadIdx.x] += add;
        __syncthreads();
    }
    int excl = sdata[threadIdx.x] - v + partials[blockIdx.x];
    if (i < N_NODES) row_ptr[i] = excl;
    if (i == N_NODES - 1) row_ptr[N_NODES] = excl + v;
}

__global__ __launch_bounds__(256) void fill_k(
    const int* __restrict__ rows, const int* __restrict__ cols,
    const float* __restrict__ vals, const int* __restrict__ row_ptr,
    int* cursor, int* __restrict__ csr_col, float* __restrict__ csr_val)
{
    int e = blockIdx.x * 256 + threadIdx.x;
    if (e >= N_EDGES) return;
    int r = rows[e];
    int pos = row_ptr[r] + atomicAdd(&cursor[r], 1);
    csr_col[pos] = cols[e];
    csr_val[pos] = vals[e];
}

// ---------------------------------------------------------------------------
// CSR gather + self + bias(already in T) + relu:
//   Y[n] = relu(T[n] + sum_{e in row n} val[e] * S[col[e]])
// One 64-lane wave per node. F4 = OUT_F/4 feature lanes (float4 each);
// EP = 64/F4 edges processed in parallel, reduced via shfl_xor at the end.
// ---------------------------------------------------------------------------
template<int OUT_F>
__global__ __launch_bounds__(256) void gather_k(
    const int* __restrict__ row_ptr, const int* __restrict__ csr_col,
    const float* __restrict__ csr_val, const float* __restrict__ S,
    const float* __restrict__ T, float* __restrict__ Y)
{
    constexpr int F4 = OUT_F / 4;      // 32 (128-wide) or 16 (64-wide)
    constexpr int EP = 64 / F4;        // 2 or 4
    int node = blockIdx.x * 4 + (threadIdx.x >> 6);
    if (node >= N_NODES) return;
    int lane = threadIdx.x & 63;
    int fl = lane & (F4 - 1);
    int ep = lane / F4;
    int start = row_ptr[node];
    int end   = row_ptr[node + 1];

    const float4* S4 = (const float4*)S;
    float4 acc = {0.f, 0.f, 0.f, 0.f};
    for (int e = start + ep; e < end; e += EP) {
        int c = csr_col[e];
        float v = csr_val[e];
        float4 sv = S4[(long)c * F4 + fl];
        acc.x = fmaf(v, sv.x, acc.x);
        acc.y = fmaf(v, sv.y, acc.y);
        acc.z = fmaf(v, sv.z, acc.z);
        acc.w = fmaf(v, sv.w, acc.w);
    }
#pragma unroll
    for (int off = F4; off < 64; off <<= 1) {
        acc.x += __shfl_xor(acc.x, off, 64);
        acc.y += __shfl_xor(acc.y, off, 64);
        acc.z += __shfl_xor(acc.z, off, 64);
        acc.w += __shfl_xor(acc.w, off, 64);
    }
    if (ep == 0) {
        float4 tv = ((const float4*)T)[(long)node * F4 + fl];
        float4 o;
        o.x = fmaxf(acc.x + tv.x, 0.f);
        o.y = fmaxf(acc.y + tv.y, 0.f);
        o.z = fmaxf(acc.z + tv.z, 0.f);
        o.w = fmaxf(acc.w + tv.w, 0.f);
        ((float4*)Y)[(long)node * F4 + fl] = o;
    }
}

extern "C" void kernel_launch(void* const* d_in, const int* in_sizes, int n_in,
                              void* d_out, int out_size, void* d_ws, size_t ws_size,
                              hipStream_t stream)
{
    const float* x     = (const float*)d_in[0];
    const int*   erows = (const int*)d_in[1];
    const int*   ecols = (const int*)d_in[2];
    const float* evals = (const float*)d_in[3];
    const float* fc1_w = (const float*)d_in[4];
    const float* fc1_b = (const float*)d_in[5];
    const float* fc2_w = (const float*)d_in[6];
    const float* fc2_b = (const float*)d_in[7];
    const float* ln_g  = (const float*)d_in[8];
    const float* ln_b  = (const float*)d_in[9];
    const float* gc_wn[4] = {(const float*)d_in[10], (const float*)d_in[13],
                             (const float*)d_in[16], (const float*)d_in[19]};
    const float* gc_wsq[4] = {(const float*)d_in[11], (const float*)d_in[14],
                              (const float*)d_in[17], (const float*)d_in[20]};
    const float* gc_b[4]  = {(const float*)d_in[12], (const float*)d_in[15],
                             (const float*)d_in[18], (const float*)d_in[21]};

    // workspace layout (~180 MB)
    float* A = (float*)d_ws;                        // [N,128]
    float* T = A + (size_t)N_NODES * 128;           // [N,128]
    float* S = T + (size_t)N_NODES * 128;           // [N,128]
    int* row_ptr  = (int*)(S + (size_t)N_NODES * 128);   // N+1
    int* cnt      = row_ptr + (N_NODES + 2);             // N
    int* partials = cnt + N_NODES;                        // 512
    int* csr_col  = partials + 512;                       // E
    float* csr_val = (float*)(csr_col + N_EDGES);         // E
    float* out = (float*)d_out;

    dim3 blk(256);
    int gemm_grid = (N_NODES + 63) / 64;
    int edge_grid = (N_EDGES + 255) / 256;
    int node_grid = (N_NODES + 3) / 4;

    // ---- CSR build (per call; deterministic work, racy order only) ----
    hipMemsetAsync(cnt, 0, (size_t)N_NODES * 4, stream);
    hist_k<<<edge_grid, blk, 0, stream>>>(erows, cnt);
    scan_phase1<<<SCAN_NBLK, blk, 0, stream>>>(cnt, partials);
    scan_phase2<<<1, 512, 0, stream>>>(partials);
    scan_phase3<<<SCAN_NBLK, blk, 0, stream>>>(cnt, partials, row_ptr);
    hipMemsetAsync(cnt, 0, (size_t)N_NODES * 4, stream);
    fill_k<<<edge_grid, blk, 0, stream>>>(erows, ecols, evals, row_ptr, cnt, csr_col, csr_val);

    // ---- MLP head ----
    gemm_k<128, true, true, true><<<gemm_grid, blk, 0, stream>>>(x, fc1_w, fc1_b, A);
    gemm_k<128, true, true, true><<<gemm_grid, blk, 0, stream>>>(A, fc2_w, fc2_b, T);
    ln_k<<<node_grid, blk, 0, stream>>>(T, ln_g, ln_b, A);

    // ---- gc1..gc3 (128->128): S = A@wn ; T = A@ws + b ; gather+relu -> A ----
    for (int l = 0; l < 3; l++) {
        gemm_k<128, false, false, false><<<gemm_grid, blk, 0, stream>>>(A, gc_wn[l], nullptr, S);
        gemm_k<128, false, false, true><<<gemm_grid, blk, 0, stream>>>(A, gc_wsq[l], gc_b[l], T);
        gather_k<128><<<node_grid, blk, 0, stream>>>(row_ptr, csr_col, csr_val, S, T, A);
    }

    // ---- gc4 (128->64): final relu straight into d_out ----
    gemm_k<64, false, false, false><<<gemm_grid, blk, 0, stream>>>(A, gc_wn[3], nullptr, S);
    gemm_k<64, false, false, true><<<gemm_grid, blk, 0, stream>>>(A, gc_wsq[3], gc_b[3], T);
    gather_k<64><<<node_grid, blk, 0, stream>>>(row_ptr, csr_col, csr_val, S, T, out);
}

// Round 3
// 1011.701 us; speedup vs baseline: 20.0315x; 2.6439x over previous
//
#include <hip/hip_runtime.h>

constexpr int N_NODES = 100000;
constexpr int N_EDGES = 3200000;
constexpr float EPS = 1e-6f;

constexpr int SCAN_CHUNK = 256;
constexpr int SCAN_NBLK = (N_NODES + SCAN_CHUNK - 1) / SCAN_CHUNK;   // 391

typedef __attribute__((ext_vector_type(8))) short bfrag;   // 8 bf16 = 4 VGPR
typedef __attribute__((ext_vector_type(4))) float ffrag;   // 4 fp32 acc

__device__ __forceinline__ unsigned short f2bf(float f) {
    unsigned int u = __float_as_uint(f);
    u += 0x7FFFu + ((u >> 16) & 1u);      // RNE
    return (unsigned short)(u >> 16);
}
__device__ __forceinline__ float bf_lo(unsigned int w) { return __uint_as_float(w << 16); }
__device__ __forceinline__ float bf_hi(unsigned int w) { return __uint_as_float(w & 0xFFFF0000u); }

// ---------------------------------------------------------------------------
// Weight prep: convert all weights to bf16, layout [out_row][k=128].
// Rows: fc1 [0,128) | fc2 [128,256) | gc l=0..2 [256+256l, +256) (wn|ws) |
//       gc3 [1024,1152) (wn|ws, 64+64)
// ---------------------------------------------------------------------------
__global__ __launch_bounds__(256) void prep_w_k(
    const float* __restrict__ fc1_w, const float* __restrict__ fc2_w,
    const float* __restrict__ wn0, const float* __restrict__ ws0,
    const float* __restrict__ wn1, const float* __restrict__ ws1,
    const float* __restrict__ wn2, const float* __restrict__ ws2,
    const float* __restrict__ wn3, const float* __restrict__ ws3,
    unsigned short* __restrict__ Wb)
{
    int idx = blockIdx.x * 256 + threadIdx.x;
    if (idx >= 1152 * 128) return;
    int r = idx >> 7, k = idx & 127;
    float v;
    if (r < 128) v = fc1_w[r * 128 + k];                 // [out,in] already
    else if (r < 256) v = fc2_w[(r - 128) * 128 + k];
    else if (r < 1024) {
        int r2 = r - 256, l = r2 >> 8, n = r2 & 255;
        const float* wn = l == 0 ? wn0 : l == 1 ? wn1 : wn2;
        const float* ws = l == 0 ? ws0 : l == 1 ? ws1 : ws2;
        v = (n < 128) ? wn[k * 128 + n] : ws[k * 128 + (n - 128)];   // transpose
    } else {
        int n = r - 1024;
        v = (n < 64) ? wn3[k * 64 + n] : ws3[k * 64 + (n - 64)];
    }
    Wb[idx] = f2bf(v);
}

// ---------------------------------------------------------------------------
// MFMA GEMM, M=100k, K=128, bf16 inputs, fp32 acc.
// Block 256 thr = 4 waves; wave does 2 m-tiles (32 nodes) x NT n-tiles.
// MODE 0: Y = relu(A@W + bias) -> bf16            (fc1)
// MODE 1: Y = LN(relu(A@W + bias)) -> bf16        (fc2 + fused LN)
// MODE 2: dual: nt<NT/2 -> S=A@Wn (bf16); nt>=NT/2 -> T=A@Ws+bias (fp32)
// LDS B layout [n][k] padded to 136 shorts/row -> ds_read_b128 conflict-free.
// ---------------------------------------------------------------------------
template<int NT, int MODE, bool A_FP32>
__global__ __launch_bounds__(256, 2) void mfma_gemm_k(
    const void* __restrict__ Av, const unsigned short* __restrict__ Wg_,
    const float* __restrict__ bias,
    const float* __restrict__ gamma, const float* __restrict__ beta,
    unsigned short* __restrict__ Yb, float* __restrict__ Tout)
{
    constexpr int ROWS = NT * 16;
    __shared__ unsigned short Bs[ROWS * 136];
    const int tid = threadIdx.x;

    // stage B (pre-converted bf16 [n][128]) into padded LDS [n][136]
    const uint4* Wg = (const uint4*)Wg_;
    uint4* Bs4 = (uint4*)Bs;
    for (int i = tid; i < ROWS * 16; i += 256) {
        int n = i >> 4, c = i & 15;
        Bs4[n * 17 + c] = Wg[i];
    }

    const int wave = tid >> 6, lane = tid & 63;
    const int quad = lane >> 4, l16 = lane & 15;
    const long base = (long)blockIdx.x * 128 + wave * 32;

    // A fragments: a[mt][t] = A[node][t*32 + quad*8 + j], j=0..7
    union AU { uint4 q; bfrag v; unsigned short s[8]; };
    bfrag a[2][4];
#pragma unroll
    for (int mt = 0; mt < 2; mt++) {
        long node = base + mt * 16 + l16;
        bool ok = node < N_NODES;
        if (A_FP32) {
            const float4* Ar = (const float4*)((const float*)Av + node * 128);
#pragma unroll
            for (int t = 0; t < 4; t++) {
                AU u;
                if (ok) {
                    float4 f0 = Ar[t * 8 + quad * 2];
                    float4 f1 = Ar[t * 8 + quad * 2 + 1];
                    u.s[0] = f2bf(f0.x); u.s[1] = f2bf(f0.y);
                    u.s[2] = f2bf(f0.z); u.s[3] = f2bf(f0.w);
                    u.s[4] = f2bf(f1.x); u.s[5] = f2bf(f1.y);
                    u.s[6] = f2bf(f1.z); u.s[7] = f2bf(f1.w);
                } else u.q = make_uint4(0, 0, 0, 0);
                a[mt][t] = u.v;
            }
        } else {
            const uint4* Ar = (const uint4*)((const unsigned short*)Av + node * 128);
#pragma unroll
            for (int t = 0; t < 4; t++) {
                AU u;
                u.q = ok ? Ar[t * 4 + quad] : make_uint4(0, 0, 0, 0);
                a[mt][t] = u.v;
            }
        }
    }
    __syncthreads();

    ffrag acc[2][NT];
#pragma unroll
    for (int mt = 0; mt < 2; mt++)
#pragma unroll
        for (int nt = 0; nt < NT; nt++) acc[mt][nt] = (ffrag)0.f;

#pragma unroll
    for (int t = 0; t < 4; t++) {
#pragma unroll
        for (int nt = 0; nt < NT; nt++) {
            bfrag b = *(const bfrag*)&Bs[(nt * 16 + l16) * 136 + t * 32 + quad * 8];
            acc[0][nt] = __builtin_amdgcn_mfma_f32_16x16x32_bf16(a[0][t], b, acc[0][nt], 0, 0, 0);
            acc[1][nt] = __builtin_amdgcn_mfma_f32_16x16x32_bf16(a[1][t], b, acc[1][nt], 0, 0, 0);
        }
    }

    // ---- epilogue ----  D: node_local = quad*4+reg, col = nt*16+l16
    if (MODE == 0) {
        float bv[NT];
#pragma unroll
        for (int nt = 0; nt < NT; nt++) bv[nt] = bias[nt * 16 + l16];
#pragma unroll
        for (int mt = 0; mt < 2; mt++)
#pragma unroll
            for (int reg = 0; reg < 4; reg++) {
                long node = base + mt * 16 + quad * 4 + reg;
                if (node >= N_NODES) continue;
#pragma unroll
                for (int nt = 0; nt < NT; nt++) {
                    float v = fmaxf(acc[mt][nt][reg] + bv[nt], 0.f);
                    Yb[node * (NT * 16) + nt * 16 + l16] = f2bf(v);
                }
            }
    } else if (MODE == 1) {
        float bv[NT], gv[NT], bev[NT];
#pragma unroll
        for (int nt = 0; nt < NT; nt++) {
            bv[nt] = bias[nt * 16 + l16];
            gv[nt] = gamma[nt * 16 + l16];
            bev[nt] = beta[nt * 16 + l16];
        }
#pragma unroll
        for (int mt = 0; mt < 2; mt++)
#pragma unroll
            for (int reg = 0; reg < 4; reg++) {
                long node = base + mt * 16 + quad * 4 + reg;
                if (node >= N_NODES) continue;
                float v[NT], s = 0.f, sq = 0.f;
#pragma unroll
                for (int nt = 0; nt < NT; nt++) {
                    v[nt] = fmaxf(acc[mt][nt][reg] + bv[nt], 0.f);
                    s += v[nt]; sq += v[nt] * v[nt];
                }
#pragma unroll
                for (int off = 1; off < 16; off <<= 1) {
                    s  += __shfl_xor(s, off, 64);
                    sq += __shfl_xor(sq, off, 64);
                }
                float mean = s * (1.f / 128.f);
                float var = fmaxf((sq - 128.f * mean * mean) * (1.f / 127.f), 0.f);
                float inv = 1.f / (sqrtf(var) + EPS);
#pragma unroll
                for (int nt = 0; nt < NT; nt++)
                    Yb[node * (NT * 16) + nt * 16 + l16] =
                        f2bf(gv[nt] * (v[nt] - mean) * inv + bev[nt]);
            }
    } else {  // MODE 2: dual S(bf16) | T(fp32)+bias
        constexpr int HALF = NT / 2;
        float bv[HALF];
#pragma unroll
        for (int i = 0; i < HALF; i++) bv[i] = bias[i * 16 + l16];
#pragma unroll
        for (int mt = 0; mt < 2; mt++)
#pragma unroll
            for (int reg = 0; reg < 4; reg++) {
                long node = base + mt * 16 + quad * 4 + reg;
                if (node >= N_NODES) continue;
#pragma unroll
                for (int nt = 0; nt < HALF; nt++)
                    Yb[node * (HALF * 16) + nt * 16 + l16] = f2bf(acc[mt][nt][reg]);
#pragma unroll
                for (int nt = HALF; nt < NT; nt++) {
                    int c = (nt - HALF) * 16 + l16;
                    Tout[node * (HALF * 16) + c] = acc[mt][nt][reg] + bv[nt - HALF];
                }
            }
    }
}

// ---------------------------------------------------------------------------
// CSR build
// ---------------------------------------------------------------------------
__global__ __launch_bounds__(256) void hist_k(const int* __restrict__ rows, int* cnt)
{
    int e = blockIdx.x * 256 + threadIdx.x;
    if (e < N_EDGES) atomicAdd(&cnt[rows[e]], 1);
}

__global__ __launch_bounds__(256) void scan_phase1(const int* __restrict__ cnt, int* partials)
{
    __shared__ int sdata[SCAN_CHUNK];
    int i = blockIdx.x * SCAN_CHUNK + threadIdx.x;
    sdata[threadIdx.x] = (i < N_NODES) ? cnt[i] : 0;
    __syncthreads();
    for (int s = SCAN_CHUNK / 2; s > 0; s >>= 1) {
        if (threadIdx.x < s) sdata[threadIdx.x] += sdata[threadIdx.x + s];
        __syncthreads();
    }
    if (threadIdx.x == 0) partials[blockIdx.x] = sdata[0];
}

__global__ __launch_bounds__(512) void scan_phase2(int* partials)
{
    __shared__ int sdata[512];
    int t = threadIdx.x;
    int v = (t < SCAN_NBLK) ? partials[t] : 0;
    sdata[t] = v;
    __syncthreads();
    for (int off = 1; off < 512; off <<= 1) {
        int add = (t >= off) ? sdata[t - off] : 0;
        __syncthreads();
        sdata[t] += add;
        __syncthreads();
    }
    if (t < SCAN_NBLK) partials[t] = sdata[t] - v;
}

__global__ __launch_bounds__(256) void scan_phase3(
    const int* __restrict__ cnt, const int* __restrict__ partials, int* row_ptr)
{
    __shared__ int sdata[SCAN_CHUNK];
    int i = blockIdx.x * SCAN_CHUNK + threadIdx.x;
    int v = (i < N_NODES) ? cnt[i] : 0;
    sdata[threadIdx.x] = v;
    __syncthreads();
    for (int off = 1; off < SCAN_CHUNK; off <<= 1) {
        int add = (threadIdx.x >= off) ? sdata[threadIdx.x - off] : 0;
        __syncthreads();
        sdata[threadIdx.x] += add;
        __syncthreads();
    }
    int excl = sdata[threadIdx.x] - v + partials[blockIdx.x];
    if (i < N_NODES) row_ptr[i] = excl;
    if (i == N_NODES - 1) row_ptr[N_NODES] = excl + v;
}

__global__ __launch_bounds__(256) void fill_k(
    const int* __restrict__ rows, const int* __restrict__ cols,
    const float* __restrict__ vals, const int* __restrict__ row_ptr,
    int* cursor, int2* __restrict__ csr)
{
    int e = blockIdx.x * 256 + threadIdx.x;
    if (e >= N_EDGES) return;
    int r = rows[e];
    int pos = row_ptr[r] + atomicAdd(&cursor[r], 1);
    csr[pos] = make_int2(cols[e], __float_as_int(vals[e]));
}

// ---------------------------------------------------------------------------
// CSR gather: Y[n] = relu(T[n] + sum val * Sb[col])   (Sb bf16, acc fp32)
// One wave / node: FL = OUT_F/8 feature lanes (16B bf16 each), EP edges par.
// ---------------------------------------------------------------------------
template<int OUT_F, bool OUT_BF16>
__global__ __launch_bounds__(256) void gather_k(
    const int* __restrict__ row_ptr, const int2* __restrict__ csr,
    const unsigned short* __restrict__ Sb, const float* __restrict__ T,
    void* __restrict__ Y)
{
    constexpr int FL = OUT_F / 8;
    int node = blockIdx.x * 4 + (threadIdx.x >> 6);
    if (node >= N_NODES) return;
    int lane = threadIdx.x & 63;
    int fl = lane & (FL - 1), ep = lane / FL;
    int s = row_ptr[node], e = row_ptr[node + 1];

    float acc[8] = {0, 0, 0, 0, 0, 0, 0, 0};
    const uint4* S4 = (const uint4*)Sb;
    for (int i = s + ep; i < e; i += 64 / FL) {
        int2 ed = csr[i];
        float v = __int_as_float(ed.y);
        uint4 sv = S4[(long)ed.x * FL + fl];
        acc[0] = fmaf(v, bf_lo(sv.x), acc[0]);
        acc[1] = fmaf(v, bf_hi(sv.x), acc[1]);
        acc[2] = fmaf(v, bf_lo(sv.y), acc[2]);
        acc[3] = fmaf(v, bf_hi(sv.y), acc[3]);
        acc[4] = fmaf(v, bf_lo(sv.z), acc[4]);
        acc[5] = fmaf(v, bf_hi(sv.z), acc[5]);
        acc[6] = fmaf(v, bf_lo(sv.w), acc[6]);
        acc[7] = fmaf(v, bf_hi(sv.w), acc[7]);
    }
#pragma unroll
    for (int off = FL; off < 64; off <<= 1)
#pragma unroll
        for (int j = 0; j < 8; j++) acc[j] += __shfl_xor(acc[j], off, 64);

    if (ep == 0) {
        const float4* T4 = (const float4*)T;
        float4 t0 = T4[(long)node * (OUT_F / 4) + fl * 2];
        float4 t1 = T4[(long)node * (OUT_F / 4) + fl * 2 + 1];
        float o[8];
        o[0] = fmaxf(acc[0] + t0.x, 0.f); o[1] = fmaxf(acc[1] + t0.y, 0.f);
        o[2] = fmaxf(acc[2] + t0.z, 0.f); o[3] = fmaxf(acc[3] + t0.w, 0.f);
        o[4] = fmaxf(acc[4] + t1.x, 0.f); o[5] = fmaxf(acc[5] + t1.y, 0.f);
        o[6] = fmaxf(acc[6] + t1.z, 0.f); o[7] = fmaxf(acc[7] + t1.w, 0.f);
        if (OUT_BF16) {
            uint4 p;
            p.x = (unsigned)f2bf(o[0]) | ((unsigned)f2bf(o[1]) << 16);
            p.y = (unsigned)f2bf(o[2]) | ((unsigned)f2bf(o[3]) << 16);
            p.z = (unsigned)f2bf(o[4]) | ((unsigned)f2bf(o[5]) << 16);
            p.w = (unsigned)f2bf(o[6]) | ((unsigned)f2bf(o[7]) << 16);
            ((uint4*)Y)[(long)node * FL + fl] = p;
        } else {
            float4* Yo = (float4*)Y;
            Yo[(long)node * (OUT_F / 4) + fl * 2]     = make_float4(o[0], o[1], o[2], o[3]);
            Yo[(long)node * (OUT_F / 4) + fl * 2 + 1] = make_float4(o[4], o[5], o[6], o[7]);
        }
    }
}

extern "C" void kernel_launch(void* const* d_in, const int* in_sizes, int n_in,
                              void* d_out, int out_size, void* d_ws, size_t ws_size,
                              hipStream_t stream)
{
    const float* x     = (const float*)d_in[0];
    const int*   erows = (const int*)d_in[1];
    const int*   ecols = (const int*)d_in[2];
    const float* evals = (const float*)d_in[3];
    const float* fc1_w = (const float*)d_in[4];
    const float* fc1_b = (const float*)d_in[5];
    const float* fc2_w = (const float*)d_in[6];
    const float* fc2_b = (const float*)d_in[7];
    const float* ln_g  = (const float*)d_in[8];
    const float* ln_b  = (const float*)d_in[9];
    const float* gc_wn[4] = {(const float*)d_in[10], (const float*)d_in[13],
                             (const float*)d_in[16], (const float*)d_in[19]};
    const float* gc_ws[4] = {(const float*)d_in[11], (const float*)d_in[14],
                             (const float*)d_in[17], (const float*)d_in[20]};
    const float* gc_b[4]  = {(const float*)d_in[12], (const float*)d_in[15],
                             (const float*)d_in[18], (const float*)d_in[21]};

    // workspace
    unsigned short* Sbf = (unsigned short*)d_ws;                 // [N,128] bf16 (also fc1 temp)
    unsigned short* Abf = Sbf + (size_t)N_NODES * 128;           // [N,128] bf16
    float* T = (float*)(Abf + (size_t)N_NODES * 128);            // [N,128] fp32
    unsigned short* Wb = (unsigned short*)(T + (size_t)N_NODES * 128);  // 1152*128 bf16
    int* row_ptr  = (int*)(Wb + 1152 * 128);                     // N+1
    int* cnt      = row_ptr + (N_NODES + 2);
    int* partials = cnt + N_NODES;
    int2* csr     = (int2*)(partials + 512);                     // [E]
    float* out = (float*)d_out;

    dim3 blk(256);
    int gemm_grid = (N_NODES + 127) / 128;        // 782
    int edge_grid = (N_EDGES + 255) / 256;
    int node_grid = (N_NODES + 3) / 4;

    // CSR build
    hipMemsetAsync(cnt, 0, (size_t)N_NODES * 4, stream);
    hist_k<<<edge_grid, blk, 0, stream>>>(erows, cnt);
    scan_phase1<<<SCAN_NBLK, blk, 0, stream>>>(cnt, partials);
    scan_phase2<<<1, 512, 0, stream>>>(partials);
    scan_phase3<<<SCAN_NBLK, blk, 0, stream>>>(cnt, partials, row_ptr);
    hipMemsetAsync(cnt, 0, (size_t)N_NODES * 4, stream);
    fill_k<<<edge_grid, blk, 0, stream>>>(erows, ecols, evals, row_ptr, cnt, csr);

    // weights -> bf16
    prep_w_k<<<(1152 * 128 + 255) / 256, blk, 0, stream>>>(
        fc1_w, fc2_w, gc_wn[0], gc_ws[0], gc_wn[1], gc_ws[1],
        gc_wn[2], gc_ws[2], gc_wn[3], gc_ws[3], Wb);

    // fc1 -> Sbf(temp bf16), fc2+LN -> Abf
    mfma_gemm_k<8, 0, true><<<gemm_grid, blk, 0, stream>>>(
        x, Wb + 0, fc1_b, nullptr, nullptr, Sbf, nullptr);
    mfma_gemm_k<8, 1, false><<<gemm_grid, blk, 0, stream>>>(
        Sbf, Wb + 128 * 128, fc2_b, ln_g, ln_b, Abf, nullptr);

    // gc1..gc3: dual GEMM (S bf16 | T fp32) + gather -> Abf
    for (int l = 0; l < 3; l++) {
        mfma_gemm_k<16, 2, false><<<gemm_grid, blk, 0, stream>>>(
            Abf, Wb + (256 + l * 256) * 128, gc_b[l], nullptr, nullptr, Sbf, T);
        gather_k<128, true><<<node_grid, blk, 0, stream>>>(row_ptr, csr, Sbf, T, Abf);
    }

    // gc4 (128->64): dual GEMM NT=8, gather -> fp32 d_out
    mfma_gemm_k<8, 2, false><<<gemm_grid, blk, 0, stream>>>(
        Abf, Wb + 1024 * 128, gc_b[3], nullptr, nullptr, Sbf, T);
    gather_k<64, false><<<node_grid, blk, 0, stream>>>(row_ptr, csr, Sbf, T, out);
}